// Round 1
// 671.369 us; speedup vs baseline: 1.1026x; 1.1026x over previous
//
#include <hip/hip_runtime.h>
#include <stdint.h>

#define N_NODES 50000
#define N_EDGES 800000

// flag indices: 0:x 1:ea 2:Wl1 3:bl1 4:Wr1 5:br1 6:We1 7:att1 8:bias1
//               9:Wl2 10:bl2 11:Wr2 12:br2 13:We2 14:att2 15:bias2
struct Ptrs { const void* p[16]; int n[16]; };

typedef __attribute__((ext_vector_type(8))) short bf16x8;
typedef __attribute__((ext_vector_type(4))) float f32x4;

__device__ __forceinline__ float bf2f(unsigned short u){
  union { unsigned int i; float f; } v; v.i = ((unsigned int)u) << 16; return v.f;
}
__device__ __forceinline__ float lo16(unsigned int u){ union { unsigned int i; float f; } v; v.i = u << 16; return v.f; }
__device__ __forceinline__ float hi16(unsigned int u){ union { unsigned int i; float f; } v; v.i = u & 0xffff0000u; return v.f; }
__device__ __forceinline__ unsigned short f2bf(float f){
  if (!(f == f)) return 0;
  unsigned int x = __float_as_uint(f);
  unsigned int r = (x + 0x7fffu + ((x >> 16) & 1u)) >> 16;
  return (unsigned short)r;
}
__device__ __forceinline__ float fin(float v){
  if (!(v == v)) return 0.f;
  return fminf(fmaxf(v, -1e30f), 1e30f);
}
__device__ __forceinline__ float loadF(const void* p, int f32, size_t idx){
  return f32 ? ((const float*)p)[idx] : bf2f(((const unsigned short*)p)[idx]);
}

// stage n bf16 elems of W (bf16 or f32 source) into LDS; n multiple of 2048
__device__ __forceinline__ void stageW(unsigned short* dst, const void* src, int n, int f32, int tid){
  if (f32) {
    for (int i = tid * 8; i < n; i += 2048) {
      float4 a = *(const float4*)((const float*)src + i);
      float4 b = *(const float4*)((const float*)src + i + 4);
      uint4 u;
      u.x = (unsigned)f2bf(a.x) | ((unsigned)f2bf(a.y) << 16);
      u.y = (unsigned)f2bf(a.z) | ((unsigned)f2bf(a.w) << 16);
      u.z = (unsigned)f2bf(b.x) | ((unsigned)f2bf(b.y) << 16);
      u.w = (unsigned)f2bf(b.z) | ((unsigned)f2bf(b.w) << 16);
      *(uint4*)(dst + i) = u;
    }
  } else {
    for (int i = tid * 8; i < n; i += 2048)
      *(uint4*)(dst + i) = *(const uint4*)((const unsigned short*)src + i);
  }
}

// ---------- dtype detect ----------
__global__ __launch_bounds__(256) void k_detect(Ptrs tl, int* __restrict__ flags)
{
  __shared__ int red[256];
  int b = blockIdx.x, t = threadIdx.x;
  const unsigned short* p = (const unsigned short*)tl.p[b];
  int n = tl.n[b]; if (n > 16384) n = 16384;
  int crazy = 0;
  for (int i = t; i < n; i += 256) {
    unsigned short u = p[i];
    if (u) {
      int ex = (u >> 7) & 0xFF;
      if (ex == 0xFF || ex < 0x60) crazy++;
    }
  }
  red[t] = crazy; __syncthreads();
  for (int off = 128; off; off >>= 1) { if (t < off) red[t] += red[t + off]; __syncthreads(); }
  if (t == 0) flags[b] = (red[0] * 10 > n) ? 1 : 0;
}

__global__ __launch_bounds__(256) void k_zero(int* __restrict__ p, int n)
{
  int i = blockIdx.x * 256 + threadIdx.x;
  if (i < n) p[i] = 0;
}

// ---------- layer-1 GEMM: xl1p / xr1p (both packed bf16 [N,64] uints) ----------
__global__ __launch_bounds__(256) void k_gemm1(
    const void* __restrict__ x,
    const void* __restrict__ Wl, const void* __restrict__ bl,
    const void* __restrict__ Wr, const void* __restrict__ br,
    const int* __restrict__ flags,
    unsigned int* __restrict__ xlp, unsigned int* __restrict__ xrp)
{
  __shared__ float xs[32 * 132];
  __shared__ unsigned short ws[128 * 128];
  const void* W  = blockIdx.y ? Wr : Wl;
  const void* bb = blockIdx.y ? br : bl;
  int fW = blockIdx.y ? flags[4] : flags[2];
  int fB = blockIdx.y ? flags[5] : flags[3];
  int fX = flags[0];
  unsigned int* outp = blockIdx.y ? xrp : xlp;
  int tid = threadIdx.x;
  int row0 = blockIdx.x * 32;
  stageW(ws, W, 128 * 128, fW, tid);
  for (int i = tid * 4; i < 32 * 128; i += 1024) {
    int r = i >> 7, k = i & 127;
    int row = row0 + r;
    float4 v = make_float4(0.f, 0.f, 0.f, 0.f);
    if (row < N_NODES) {
      if (fX) v = *(const float4*)((const float*)x + (size_t)row * 128 + k);
      else {
        uint2 u = *(const uint2*)((const unsigned short*)x + (size_t)row * 128 + k);
        v.x = lo16(u.x); v.y = hi16(u.x); v.z = lo16(u.y); v.w = hi16(u.y);
      }
    }
    *(float4*)(xs + r * 132 + k) = v;
  }
  __syncthreads();
  int r = tid >> 3, cg = tid & 7;
  float acc[16];
#pragma unroll
  for (int j = 0; j < 16; j++) acc[j] = 0.f;
#pragma unroll 4
  for (int k = 0; k < 128; k++) {
    float xv = xs[r * 132 + k];
    uint4 p0 = *(const uint4*)(ws + k * 128 + cg * 8);
    uint4 p1 = *(const uint4*)(ws + k * 128 + 64 + cg * 8);
    acc[0]  = fmaf(xv, lo16(p0.x), acc[0]);  acc[1]  = fmaf(xv, hi16(p0.x), acc[1]);
    acc[2]  = fmaf(xv, lo16(p0.y), acc[2]);  acc[3]  = fmaf(xv, hi16(p0.y), acc[3]);
    acc[4]  = fmaf(xv, lo16(p0.z), acc[4]);  acc[5]  = fmaf(xv, hi16(p0.z), acc[5]);
    acc[6]  = fmaf(xv, lo16(p0.w), acc[6]);  acc[7]  = fmaf(xv, hi16(p0.w), acc[7]);
    acc[8]  = fmaf(xv, lo16(p1.x), acc[8]);  acc[9]  = fmaf(xv, hi16(p1.x), acc[9]);
    acc[10] = fmaf(xv, lo16(p1.y), acc[10]); acc[11] = fmaf(xv, hi16(p1.y), acc[11]);
    acc[12] = fmaf(xv, lo16(p1.z), acc[12]); acc[13] = fmaf(xv, hi16(p1.z), acc[13]);
    acc[14] = fmaf(xv, lo16(p1.w), acc[14]); acc[15] = fmaf(xv, hi16(p1.w), acc[15]);
  }
  int row = row0 + r;
  if (row < N_NODES) {
    unsigned int* op = outp + (size_t)row * 64;
    uint4 o;
    unsigned int* ou = (unsigned int*)&o;
#pragma unroll
    for (int t = 0; t < 4; t++) {
      float f0 = fin(acc[2 * t]     + loadF(bb, fB, cg * 8 + 2 * t));
      float f1 = fin(acc[2 * t + 1] + loadF(bb, fB, cg * 8 + 2 * t + 1));
      ou[t] = (unsigned)f2bf(f0) | ((unsigned)f2bf(f1) << 16);
    }
    *(uint4*)(op + cg * 4) = o;
#pragma unroll
    for (int t = 0; t < 4; t++) {
      float f0 = fin(acc[8 + 2 * t]     + loadF(bb, fB, 64 + cg * 8 + 2 * t));
      float f1 = fin(acc[8 + 2 * t + 1] + loadF(bb, fB, 64 + cg * 8 + 2 * t + 1));
      ou[t] = (unsigned)f2bf(f0) | ((unsigned)f2bf(f1) << 16);
    }
    *(uint4*)(op + 32 + cg * 4) = o;
  }
}

// ---------- layer-2 GEMM: xl2p / xr2p (packed bf16 [N,32] uints) ----------
__global__ __launch_bounds__(256) void k_gemm2(
    const float* __restrict__ h,
    const void* __restrict__ Wl, const void* __restrict__ bl,
    const void* __restrict__ Wr, const void* __restrict__ br,
    const int* __restrict__ flags,
    unsigned int* __restrict__ xlp, unsigned int* __restrict__ xrp)
{
  __shared__ float hs[32 * 132];
  __shared__ unsigned short ws[128 * 64];
  const void* W  = blockIdx.y ? Wr : Wl;
  const void* bb = blockIdx.y ? br : bl;
  int fW = blockIdx.y ? flags[11] : flags[9];
  int fB = blockIdx.y ? flags[12] : flags[10];
  unsigned int* outp = blockIdx.y ? xrp : xlp;
  int tid = threadIdx.x;
  int row0 = blockIdx.x * 32;
  stageW(ws, W, 128 * 64, fW, tid);
  for (int i = tid * 4; i < 32 * 128; i += 1024) {
    int r = i >> 7, k = i & 127;
    int row = row0 + r;
    float4 v = make_float4(0.f, 0.f, 0.f, 0.f);
    if (row < N_NODES) v = *(const float4*)(h + (size_t)row * 128 + k);
    *(float4*)(hs + r * 132 + k) = v;
  }
  __syncthreads();
  int r = tid >> 3, cg = tid & 7;
  float acc[8];
#pragma unroll
  for (int j = 0; j < 8; j++) acc[j] = 0.f;
#pragma unroll 4
  for (int k = 0; k < 128; k++) {
    float hv = hs[r * 132 + k];
    uint4 p = *(const uint4*)(ws + k * 64 + cg * 8);
    acc[0] = fmaf(hv, lo16(p.x), acc[0]); acc[1] = fmaf(hv, hi16(p.x), acc[1]);
    acc[2] = fmaf(hv, lo16(p.y), acc[2]); acc[3] = fmaf(hv, hi16(p.y), acc[3]);
    acc[4] = fmaf(hv, lo16(p.z), acc[4]); acc[5] = fmaf(hv, hi16(p.z), acc[5]);
    acc[6] = fmaf(hv, lo16(p.w), acc[6]); acc[7] = fmaf(hv, hi16(p.w), acc[7]);
  }
  int row = row0 + r;
  if (row < N_NODES) {
    uint4 o;
    unsigned int* ou = (unsigned int*)&o;
#pragma unroll
    for (int t = 0; t < 4; t++) {
      float f0 = fin(acc[2 * t]     + loadF(bb, fB, cg * 8 + 2 * t));
      float f1 = fin(acc[2 * t + 1] + loadF(bb, fB, cg * 8 + 2 * t + 1));
      ou[t] = (unsigned)f2bf(f0) | ((unsigned)f2bf(f1) << 16);
    }
    *(uint4*)(outp + (size_t)row * 32 + cg * 4) = o;
  }
}

// ---------- CSR build ----------
__global__ __launch_bounds__(256) void k_hist(const int* __restrict__ ei, int* __restrict__ counts)
{
  int e = blockIdx.x * 256 + threadIdx.x;
  if (e < N_EDGES) {
    int d = ei[N_EDGES + e]; if ((unsigned)d >= N_NODES) d = 0;
    atomicAdd(&counts[d], 1);
  }
}

__global__ __launch_bounds__(256) void k_scan1(const int* __restrict__ counts,
                                               int* __restrict__ row_ptr, int* __restrict__ bsum)
{
  __shared__ int lds[256];
  int t = threadIdx.x;
  int base = blockIdx.x * 1024 + t * 4;
  int c0 = (base + 0) < N_NODES ? counts[base + 0] : 0;
  int c1 = (base + 1) < N_NODES ? counts[base + 1] : 0;
  int c2 = (base + 2) < N_NODES ? counts[base + 2] : 0;
  int c3 = (base + 3) < N_NODES ? counts[base + 3] : 0;
  int s = c0 + c1 + c2 + c3;
  lds[t] = s; __syncthreads();
  for (int off = 1; off < 256; off <<= 1) {
    int v = (t >= off) ? lds[t - off] : 0;
    __syncthreads();
    lds[t] += v;
    __syncthreads();
  }
  int incl = lds[t];
  int excl = incl - s;
  if (base + 0 < N_NODES) row_ptr[base + 0] = excl;
  if (base + 1 < N_NODES) row_ptr[base + 1] = excl + c0;
  if (base + 2 < N_NODES) row_ptr[base + 2] = excl + c0 + c1;
  if (base + 3 < N_NODES) row_ptr[base + 3] = excl + c0 + c1 + c2;
  if (t == 255) bsum[blockIdx.x] = incl;
}

__global__ __launch_bounds__(64) void k_scan2(int* __restrict__ bsum, int nb)
{
  __shared__ int l[64];
  int t = threadIdx.x;
  if (t < nb) l[t] = bsum[t];
  __syncthreads();
  if (t == 0) { int run = 0; for (int i = 0; i < nb; i++) { int v = l[i]; l[i] = run; run += v; } }
  __syncthreads();
  if (t < nb) bsum[t] = l[t];
}

__global__ __launch_bounds__(256) void k_scan3(int* __restrict__ row_ptr, int* __restrict__ cursor,
                                               const int* __restrict__ bsum)
{
  int t = threadIdx.x;
  int base = blockIdx.x * 1024 + t * 4;
  int add = bsum[blockIdx.x];
#pragma unroll
  for (int j = 0; j < 4; j++) {
    int i = base + j;
    if (i < N_NODES) { int v = row_ptr[i] + add; row_ptr[i] = v; cursor[i] = v; }
  }
  if (blockIdx.x == 0 && t == 0) row_ptr[N_NODES] = N_EDGES;
}

// scatter now also records dst per CSR slot (score kernels run CSR-ordered)
__global__ __launch_bounds__(256) void k_scatter(const int* __restrict__ ei,
                                                 int* __restrict__ cursor, int* __restrict__ col,
                                                 int* __restrict__ srcs, int* __restrict__ dsts)
{
  int e = blockIdx.x * 256 + threadIdx.x;
  if (e < N_EDGES) {
    int d = ei[N_EDGES + e]; if ((unsigned)d >= N_NODES) d = 0;
    int s = ei[e];           if ((unsigned)s >= N_NODES) s = 0;
    int p = atomicAdd(&cursor[d], 1);
    if ((unsigned)p < N_EDGES) { col[p] = e; srcs[p] = s; dsts[p] = d; }
  }
}

// ---------- layer-1 edge scores, CSR-ordered ----------
// block = 128 CSR positions (4 waves x 2 tiles of 16). xr[dst] is L1-hot
// (consecutive p share dst); xl gathers for both tiles hoisted for MLP.
// Also emits eap: bf16 CSR-ordered copy of edge_attr for k_score2.
#define SCORE1_TILE(bfrag, xv, rv, pidx)                                       \
  {                                                                            \
    float ph0 = 0.f, ph1 = 0.f, ph2 = 0.f, ph3 = 0.f;                          \
    _Pragma("unroll")                                                          \
    for (int t = 0; t < 8; t++) {                                              \
      f32x4 c = {0.f, 0.f, 0.f, 0.f};                                          \
      c = __builtin_amdgcn_mfma_f32_16x16x32_bf16(af[t], bfrag, c, 0, 0, 0);   \
      float4 av = *(const float4*)(at + t * 16 + quad * 4);                    \
      float z0 = c[0] + lo16(xv[t].x) + lo16(rv[t].x);                         \
      float z1 = c[1] + hi16(xv[t].x) + hi16(rv[t].x);                         \
      float z2 = c[2] + lo16(xv[t].y) + lo16(rv[t].y);                         \
      float z3 = c[3] + hi16(xv[t].y) + hi16(rv[t].y);                         \
      z0 = z0 > 0.f ? z0 : 0.2f * z0;                                          \
      z1 = z1 > 0.f ? z1 : 0.2f * z1;                                          \
      z2 = z2 > 0.f ? z2 : 0.2f * z2;                                          \
      z3 = z3 > 0.f ? z3 : 0.2f * z3;                                          \
      float pp = fmaf(av.x, z0, fmaf(av.y, z1, fmaf(av.z, z2, av.w * z3)));    \
      if (t < 2)      ph0 += pp;                                               \
      else if (t < 4) ph1 += pp;                                               \
      else if (t < 6) ph2 += pp;                                               \
      else            ph3 += pp;                                               \
    }                                                                          \
    ph0 += __shfl_xor(ph0, 16, 64); ph0 += __shfl_xor(ph0, 32, 64);            \
    ph1 += __shfl_xor(ph1, 16, 64); ph1 += __shfl_xor(ph1, 32, 64);            \
    ph2 += __shfl_xor(ph2, 16, 64); ph2 += __shfl_xor(ph2, 32, 64);            \
    ph3 += __shfl_xor(ph3, 16, 64); ph3 += __shfl_xor(ph3, 32, 64);            \
    float myp = quad == 0 ? ph0 : quad == 1 ? ph1 : quad == 2 ? ph2 : ph3;     \
    w1[(size_t)(pidx) * 4 + quad] = __expf(fminf(fin(myp), 25.f));             \
  }

__global__ __launch_bounds__(256, 3) void k_score1(
    const void* __restrict__ ea, const int* __restrict__ col,
    const int* __restrict__ srcs, const int* __restrict__ dsts,
    const unsigned int* __restrict__ xlp, const unsigned int* __restrict__ xrp,
    const void* __restrict__ We, const void* __restrict__ att,
    const int* __restrict__ flags, float* __restrict__ w1,
    unsigned short* __restrict__ eap)
{
  __shared__ unsigned short wt[128 * 34];   // WeT[ch][k], stride 34 (odd dwords)
  __shared__ float at[128];
  int tid = threadIdx.x;
  {
    int f = flags[6];
    for (int i = tid; i < 4096; i += 256) {   // We[k][c] -> wt[c*34+k]
      int k = i >> 7, c = i & 127;
      wt[c * 34 + k] = f ? f2bf(((const float*)We)[i]) : ((const unsigned short*)We)[i];
    }
  }
  if (tid < 128) at[tid] = loadF(att, flags[7], tid);
  __syncthreads();
  int lane = tid & 63;
  int idx16 = lane & 15, quad = lane >> 4;
  bf16x8 af[8];
#pragma unroll
  for (int t = 0; t < 8; t++)
    af[t] = *(const bf16x8*)(wt + (t * 16 + idx16) * 34 + quad * 8);
  int fEA = flags[1];
  int pA = blockIdx.x * 128 + (tid >> 6) * 32 + idx16;
  int pB = pA + 16;
  int eA = col[pA], eB = col[pB];
  int sA = srcs[pA], sB = srcs[pB];
  int dA = dsts[pA], dB = dsts[pB];
  // edge-attr fragments (gathered via col)
  bf16x8 bA, bB;
  if (fEA) {
    const float* pa = (const float*)ea + (size_t)eA * 32 + quad * 8;
    const float* pb = (const float*)ea + (size_t)eB * 32 + quad * 8;
    float4 a0 = *(const float4*)pa;
    float4 a1 = *(const float4*)(pa + 4);
    float4 b0 = *(const float4*)pb;
    float4 b1 = *(const float4*)(pb + 4);
    unsigned short ta[8] = { f2bf(a0.x), f2bf(a0.y), f2bf(a0.z), f2bf(a0.w),
                             f2bf(a1.x), f2bf(a1.y), f2bf(a1.z), f2bf(a1.w) };
    unsigned short tb[8] = { f2bf(b0.x), f2bf(b0.y), f2bf(b0.z), f2bf(b0.w),
                             f2bf(b1.x), f2bf(b1.y), f2bf(b1.z), f2bf(b1.w) };
    bA = *(const bf16x8*)ta;
    bB = *(const bf16x8*)tb;
  } else {
    bA = *(const bf16x8*)((const unsigned short*)ea + (size_t)eA * 32 + quad * 8);
    bB = *(const bf16x8*)((const unsigned short*)ea + (size_t)eB * 32 + quad * 8);
  }
  // CSR-ordered bf16 copy for k_score2 (sequential, coalesced)
  *(bf16x8*)(eap + (size_t)pA * 32 + quad * 8) = bA;
  *(bf16x8*)(eap + (size_t)pB * 32 + quad * 8) = bB;
  // hoisted gathers: xl random, xr L1-hot (same dst across the 16-group)
  uint2 xA[8], xB[8], rA[8], rB[8];
#pragma unroll
  for (int t = 0; t < 8; t++) xA[t] = *(const uint2*)(xlp + (size_t)sA * 64 + t * 8 + quad * 2);
#pragma unroll
  for (int t = 0; t < 8; t++) xB[t] = *(const uint2*)(xlp + (size_t)sB * 64 + t * 8 + quad * 2);
#pragma unroll
  for (int t = 0; t < 8; t++) rA[t] = *(const uint2*)(xrp + (size_t)dA * 64 + t * 8 + quad * 2);
#pragma unroll
  for (int t = 0; t < 8; t++) rB[t] = *(const uint2*)(xrp + (size_t)dB * 64 + t * 8 + quad * 2);
  SCORE1_TILE(bA, xA, rA, pA)
  SCORE1_TILE(bB, xB, rB, pB)
}

// ---------- layer-2 edge scores, CSR-ordered, reads pre-packed eap ----------
#define SCORE2_TILE(bfrag, xv, rv, pidx)                                       \
  {                                                                            \
    float ph = 0.f;                                                            \
    _Pragma("unroll")                                                          \
    for (int t = 0; t < 4; t++) {                                              \
      f32x4 c = {0.f, 0.f, 0.f, 0.f};                                          \
      c = __builtin_amdgcn_mfma_f32_16x16x32_bf16(af[t], bfrag, c, 0, 0, 0);   \
      float4 av = *(const float4*)(at + t * 16 + quad * 4);                    \
      float z0 = c[0] + lo16(xv[t].x) + lo16(rv[t].x);                         \
      float z1 = c[1] + hi16(xv[t].x) + hi16(rv[t].x);                         \
      float z2 = c[2] + lo16(xv[t].y) + lo16(rv[t].y);                         \
      float z3 = c[3] + hi16(xv[t].y) + hi16(rv[t].y);                         \
      z0 = z0 > 0.f ? z0 : 0.2f * z0;                                          \
      z1 = z1 > 0.f ? z1 : 0.2f * z1;                                          \
      z2 = z2 > 0.f ? z2 : 0.2f * z2;                                          \
      z3 = z3 > 0.f ? z3 : 0.2f * z3;                                          \
      ph += fmaf(av.x, z0, fmaf(av.y, z1, fmaf(av.z, z2, av.w * z3)));         \
    }                                                                          \
    ph += __shfl_xor(ph, 16, 64);                                              \
    ph += __shfl_xor(ph, 32, 64);                                              \
    if (quad == 0) w2[pidx] = __expf(fminf(fin(ph), 25.f));                    \
  }

__global__ __launch_bounds__(256, 4) void k_score2(
    const unsigned short* __restrict__ eap,
    const int* __restrict__ srcs, const int* __restrict__ dsts,
    const unsigned int* __restrict__ xlp, const unsigned int* __restrict__ xrp,
    const void* __restrict__ We, const void* __restrict__ att,
    const int* __restrict__ flags, float* __restrict__ w2)
{
  __shared__ unsigned short wt[64 * 34];
  __shared__ float at[64];
  int tid = threadIdx.x;
  {
    int f = flags[13];
    for (int i = tid; i < 2048; i += 256) {   // We[k][c] -> wt[c*34+k]
      int k = i >> 6, c = i & 63;
      wt[c * 34 + k] = f ? f2bf(((const float*)We)[i]) : ((const unsigned short*)We)[i];
    }
  }
  if (tid < 64) at[tid] = loadF(att, flags[14], tid);
  __syncthreads();
  int lane = tid & 63;
  int idx16 = lane & 15, quad = lane >> 4;
  bf16x8 af[4];
#pragma unroll
  for (int t = 0; t < 4; t++)
    af[t] = *(const bf16x8*)(wt + (t * 16 + idx16) * 34 + quad * 8);
  int pA = blockIdx.x * 128 + (tid >> 6) * 32 + idx16;
  int pB = pA + 16;
  int sA = srcs[pA], sB = srcs[pB];
  int dA = dsts[pA], dB = dsts[pB];
  bf16x8 bA = *(const bf16x8*)(eap + (size_t)pA * 32 + quad * 8);
  bf16x8 bB = *(const bf16x8*)(eap + (size_t)pB * 32 + quad * 8);
  uint2 xA[4], xB[4], rA[4], rB[4];
#pragma unroll
  for (int t = 0; t < 4; t++) xA[t] = *(const uint2*)(xlp + (size_t)sA * 32 + t * 8 + quad * 2);
#pragma unroll
  for (int t = 0; t < 4; t++) xB[t] = *(const uint2*)(xlp + (size_t)sB * 32 + t * 8 + quad * 2);
#pragma unroll
  for (int t = 0; t < 4; t++) rA[t] = *(const uint2*)(xrp + (size_t)dA * 32 + t * 8 + quad * 2);
#pragma unroll
  for (int t = 0; t < 4; t++) rB[t] = *(const uint2*)(xrp + (size_t)dB * 32 + t * 8 + quad * 2);
  SCORE2_TILE(bA, xA, rA, pA)
  SCORE2_TILE(bB, xB, rB, pB)
}

// ---------- layer-1 aggregate: wide (uint4) gathers, lane=(je,chunk) ----------
// wave per node. je = edge-slot (4 edges in flight / wave instr), chunk = 16B
// column of the 256B row. Reduce over je via shfl_xor(16,32) at the end.
__global__ __launch_bounds__(256) void k_agg1(
    const int* __restrict__ srcs, const int* __restrict__ row_ptr,
    const unsigned int* __restrict__ xlp, const float* __restrict__ w1,
    const void* __restrict__ bias, const int* __restrict__ flags,
    float* __restrict__ hout)
{
  int tid = threadIdx.x;
  int i = blockIdx.x * 4 + (tid >> 6);
  int lane = tid & 63;
  int je = lane >> 4;        // 0..3
  int chunk = lane & 15;     // uints chunk*4..+3 = channels chunk*8..+7
  int head = chunk >> 2;
  int p0 = row_ptr[i], p1 = row_ptr[i + 1];
  float acc[8];
#pragma unroll
  for (int k = 0; k < 8; k++) acc[k] = 0.f;
  float den = 0.f;
  int j = p0 + je;
  for (; j + 4 < p1; j += 8) {
    int s0 = srcs[j], s1 = srcs[j + 4];
    float wa = w1[(size_t)j * 4 + head];
    float wb = w1[(size_t)(j + 4) * 4 + head];
    uint4 u0 = *(const uint4*)(xlp + (size_t)s0 * 64 + chunk * 4);
    uint4 u1 = *(const uint4*)(xlp + (size_t)s1 * 64 + chunk * 4);
    acc[0] = fmaf(wa, lo16(u0.x), acc[0]); acc[1] = fmaf(wa, hi16(u0.x), acc[1]);
    acc[2] = fmaf(wa, lo16(u0.y), acc[2]); acc[3] = fmaf(wa, hi16(u0.y), acc[3]);
    acc[4] = fmaf(wa, lo16(u0.z), acc[4]); acc[5] = fmaf(wa, hi16(u0.z), acc[5]);
    acc[6] = fmaf(wa, lo16(u0.w), acc[6]); acc[7] = fmaf(wa, hi16(u0.w), acc[7]);
    acc[0] = fmaf(wb, lo16(u1.x), acc[0]); acc[1] = fmaf(wb, hi16(u1.x), acc[1]);
    acc[2] = fmaf(wb, lo16(u1.y), acc[2]); acc[3] = fmaf(wb, hi16(u1.y), acc[3]);
    acc[4] = fmaf(wb, lo16(u1.z), acc[4]); acc[5] = fmaf(wb, hi16(u1.z), acc[5]);
    acc[6] = fmaf(wb, lo16(u1.w), acc[6]); acc[7] = fmaf(wb, hi16(u1.w), acc[7]);
    den += wa + wb;
  }
  if (j < p1) {
    int s0 = srcs[j];
    float wa = w1[(size_t)j * 4 + head];
    uint4 u0 = *(const uint4*)(xlp + (size_t)s0 * 64 + chunk * 4);
    acc[0] = fmaf(wa, lo16(u0.x), acc[0]); acc[1] = fmaf(wa, hi16(u0.x), acc[1]);
    acc[2] = fmaf(wa, lo16(u0.y), acc[2]); acc[3] = fmaf(wa, hi16(u0.y), acc[3]);
    acc[4] = fmaf(wa, lo16(u0.z), acc[4]); acc[5] = fmaf(wa, hi16(u0.z), acc[5]);
    acc[6] = fmaf(wa, lo16(u0.w), acc[6]); acc[7] = fmaf(wa, hi16(u0.w), acc[7]);
    den += wa;
  }
#pragma unroll
  for (int k = 0; k < 8; k++) {
    acc[k] += __shfl_xor(acc[k], 16, 64);
    acc[k] += __shfl_xor(acc[k], 32, 64);
  }
  den += __shfl_xor(den, 16, 64);
  den += __shfl_xor(den, 32, 64);
  if (je == 0) {
    float inv = 1.f / (den + 1e-16f);
    float o[8];
#pragma unroll
    for (int k = 0; k < 8; k++) {
      float v = fin(fmaf(acc[k], inv, loadF(bias, flags[8], chunk * 8 + k)));
      o[k] = v > 0.f ? v : __expf(v) - 1.f;
    }
    *(float4*)(hout + (size_t)i * 128 + chunk * 8)     = make_float4(o[0], o[1], o[2], o[3]);
    *(float4*)(hout + (size_t)i * 128 + chunk * 8 + 4) = make_float4(o[4], o[5], o[6], o[7]);
  }
}

// ---------- layer-2 aggregate: wide (uint4) gathers, lane=(je,chunk) ----------
__global__ __launch_bounds__(256) void k_agg2(
    const int* __restrict__ srcs, const int* __restrict__ row_ptr,
    const unsigned int* __restrict__ xlp, const float* __restrict__ w2,
    const void* __restrict__ bias, const int* __restrict__ flags,
    void* __restrict__ out)
{
  int tid = threadIdx.x;
  int i = blockIdx.x * 4 + (tid >> 6);
  int lane = tid & 63;
  int je = lane >> 3;        // 0..7
  int chunk = lane & 7;      // uints chunk*4..+3 = channels chunk*8..+7
  int p0 = row_ptr[i], p1 = row_ptr[i + 1];
  float acc[8];
#pragma unroll
  for (int k = 0; k < 8; k++) acc[k] = 0.f;
  float den = 0.f;
  int j = p0 + je;
  for (; j + 8 < p1; j += 16) {
    int s0 = srcs[j], s1 = srcs[j + 8];
    float wa = w2[j], wb = w2[j + 8];
    uint4 u0 = *(const uint4*)(xlp + (size_t)s0 * 32 + chunk * 4);
    uint4 u1 = *(const uint4*)(xlp + (size_t)s1 * 32 + chunk * 4);
    acc[0] = fmaf(wa, lo16(u0.x), acc[0]); acc[1] = fmaf(wa, hi16(u0.x), acc[1]);
    acc[2] = fmaf(wa, lo16(u0.y), acc[2]); acc[3] = fmaf(wa, hi16(u0.y), acc[3]);
    acc[4] = fmaf(wa, lo16(u0.z), acc[4]); acc[5] = fmaf(wa, hi16(u0.z), acc[5]);
    acc[6] = fmaf(wa, lo16(u0.w), acc[6]); acc[7] = fmaf(wa, hi16(u0.w), acc[7]);
    acc[0] = fmaf(wb, lo16(u1.x), acc[0]); acc[1] = fmaf(wb, hi16(u1.x), acc[1]);
    acc[2] = fmaf(wb, lo16(u1.y), acc[2]); acc[3] = fmaf(wb, hi16(u1.y), acc[3]);
    acc[4] = fmaf(wb, lo16(u1.z), acc[4]); acc[5] = fmaf(wb, hi16(u1.z), acc[5]);
    acc[6] = fmaf(wb, lo16(u1.w), acc[6]); acc[7] = fmaf(wb, hi16(u1.w), acc[7]);
    den += wa + wb;
  }
  if (j < p1) {
    int s0 = srcs[j];
    float wa = w2[j];
    uint4 u0 = *(const uint4*)(xlp + (size_t)s0 * 32 + chunk * 4);
    acc[0] = fmaf(wa, lo16(u0.x), acc[0]); acc[1] = fmaf(wa, hi16(u0.x), acc[1]);
    acc[2] = fmaf(wa, lo16(u0.y), acc[2]); acc[3] = fmaf(wa, hi16(u0.y), acc[3]);
    acc[4] = fmaf(wa, lo16(u0.z), acc[4]); acc[5] = fmaf(wa, hi16(u0.z), acc[5]);
    acc[6] = fmaf(wa, lo16(u0.w), acc[6]); acc[7] = fmaf(wa, hi16(u0.w), acc[7]);
    den += wa;
  }
#pragma unroll
  for (int k = 0; k < 8; k++) {
    acc[k] += __shfl_xor(acc[k], 8, 64);
    acc[k] += __shfl_xor(acc[k], 16, 64);
    acc[k] += __shfl_xor(acc[k], 32, 64);
  }
  den += __shfl_xor(den, 8, 64);
  den += __shfl_xor(den, 16, 64);
  den += __shfl_xor(den, 32, 64);
  if (je == 0) {
    float inv = 1.f / (den + 1e-16f);
    float o[8];
#pragma unroll
    for (int k = 0; k < 8; k++)
      o[k] = fin(fmaf(acc[k], inv, loadF(bias, flags[15], chunk * 8 + k)));
    if (flags[0]) {
      float* op = (float*)out + (size_t)i * 64 + chunk * 8;
      *(float4*)(op)     = make_float4(o[0], o[1], o[2], o[3]);
      *(float4*)(op + 4) = make_float4(o[4], o[5], o[6], o[7]);
    } else {
      uint4 u;
      unsigned int* uu = (unsigned int*)&u;
#pragma unroll
      for (int t = 0; t < 4; t++)
        uu[t] = (unsigned)f2bf(o[2 * t]) | ((unsigned)f2bf(o[2 * t + 1]) << 16);
      *(uint4*)((unsigned short*)out + (size_t)i * 64 + chunk * 8) = u;
    }
  }
}

extern "C" void kernel_launch(void* const* d_in, const int* in_sizes, int n_in,
                              void* d_out, int out_size, void* d_ws, size_t ws_size,
                              hipStream_t stream)
{
  (void)n_in; (void)out_size; (void)ws_size;
  const void* x    = d_in[0];
  const int*  ei   = (const int*)d_in[1];
  const void* ea   = d_in[2];
  const void* Wl1  = d_in[3];
  const void* bl1  = d_in[4];
  const void* Wr1  = d_in[5];
  const void* br1  = d_in[6];
  const void* We1  = d_in[7];
  const void* att1 = d_in[8];
  const void* bias1= d_in[9];
  const void* Wl2  = d_in[10];
  const void* bl2  = d_in[11];
  const void* Wr2  = d_in[12];
  const void* br2  = d_in[13];
  const void* We2  = d_in[14];
  const void* att2 = d_in[15];
  const void* bias2= d_in[16];

  char* ws = (char*)d_ws;
  size_t off = 0;
  auto take = [&](size_t bytes) -> char* {
    char* p = ws + off;
    off += (bytes + 255) & ~(size_t)255;
    return p;
  };
  unsigned int* xl1p = (unsigned int*)take((size_t)N_NODES * 64 * 4);   // 12.8 MB
  unsigned int* xr1p = (unsigned int*)take((size_t)N_NODES * 64 * 4);   // 12.8 MB
  float* hbuf   = (float*)take((size_t)N_NODES * 128 * 4);              // 25.6 MB
  float* w1     = (float*)take((size_t)N_EDGES * 4 * 4);                // 12.8 MB
  unsigned short* eap = (unsigned short*)take((size_t)N_EDGES * 32 * 2);// 51.2 MB
  int*   counts = (int*)  take((size_t)N_NODES * 4);
  int*   row_ptr= (int*)  take((size_t)(N_NODES + 1) * 4);
  int*   cursor = (int*)  take((size_t)N_NODES * 4);
  int*   col    = (int*)  take((size_t)N_EDGES * 4);
  int*   srcs   = (int*)  take((size_t)N_EDGES * 4);
  int*   dsts   = (int*)  take((size_t)N_EDGES * 4);
  int*   bsum   = (int*)  take(64 * 4);
  int*   flags  = (int*)  take(64 * 4);
  unsigned int* xl2p = xl1p;      // layer-2 reuses ([N,32] <= [N,64])
  unsigned int* xr2p = xr1p;
  float* w2 = w1;                 // [E] <= [E,4]

  Ptrs tl;
  const int map[16] = {0, 2, 3, 4, 5, 6, 7, 8, 9, 10, 11, 12, 13, 14, 15, 16};
  for (int j = 0; j < 16; j++) { tl.p[j] = d_in[map[j]]; tl.n[j] = in_sizes[map[j]]; }

  int nb = (N_NODES + 1023) / 1024;
  k_detect<<<16, 256, 0, stream>>>(tl, flags);
  k_zero<<<(N_NODES + 255) / 256, 256, 0, stream>>>(counts, N_NODES);
  k_gemm1<<<dim3((N_NODES + 31) / 32, 2), 256, 0, stream>>>(x, Wl1, bl1, Wr1, br1, flags, xl1p, xr1p);
  k_hist<<<(N_EDGES + 255) / 256, 256, 0, stream>>>(ei, counts);
  k_scan1<<<nb, 256, 0, stream>>>(counts, row_ptr, bsum);
  k_scan2<<<1, 64, 0, stream>>>(bsum, nb);
  k_scan3<<<nb, 256, 0, stream>>>(row_ptr, cursor, bsum);
  k_scatter<<<(N_EDGES + 255) / 256, 256, 0, stream>>>(ei, cursor, col, srcs, dsts);
  k_score1<<<N_EDGES / 128, 256, 0, stream>>>(ea, col, srcs, dsts, xl1p, xr1p, We1, att1, flags, w1, eap);
  k_agg1<<<N_NODES / 4, 256, 0, stream>>>(srcs, row_ptr, xl1p, w1, bias1, flags, hbuf);
  k_gemm2<<<dim3((N_NODES + 31) / 32, 2), 256, 0, stream>>>(hbuf, Wl2, bl2, Wr2, br2, flags, xl2p, xr2p);
  k_score2<<<N_EDGES / 128, 256, 0, stream>>>(eap, srcs, dsts, xl2p, xr2p, We2, att2, flags, w2);
  k_agg2<<<N_NODES / 4, 256, 0, stream>>>(srcs, row_ptr, xl2p, w2, bias2, flags, d_out);
}